// Round 1
// baseline (109.252 us; speedup 1.0000x reference)
//
#include <hip/hip_runtime.h>
#include <hip/hip_bf16.h>
#include <hip/hip_fp16.h>

// Problem constants
#define DM   256
#define NH   8
#define HC   32
#define SEQ  512
#define MTOT 1024

// ---------- workspace layout (byte offsets) ----------
#define B_X1   0            // fp32 x1 [1024][256]      1 MB
#define B_QH   (1u<<20)     // fp16 q  [16][512][32]    512 KB
#define B_KH   0x180000u    // fp16 k  [16][512][32]    512 KB
#define B_VT   0x200000u    // bf16 vT [16][32][512]    512 KB
#define B_WFCT 0x280000u    // bf16 WfcT  [1024][256]   512 KB
#define B_WPJT 0x300000u    // bf16 WprojT [256][1024]  512 KB

typedef __attribute__((ext_vector_type(8))) __bf16 bf16x8;
typedef __attribute__((ext_vector_type(4))) __bf16 bf16x4;
typedef __attribute__((ext_vector_type(4))) float  f32x4;

__device__ __forceinline__ float qgelu(float x) {
    return x / (1.0f + __expf(-1.702f * x));
}

// ---------------------------------------------------------------------------
// K1: QKV GEMM (1024x768, K=256) + side-car weight transposes.
// NEW (this round): the block's shared B-panel W[0:256][n0:n0+16] is staged
// ONCE through LDS (coalesced float4 global reads, bf16 [n][k] transposed,
// stride 264 to break bank aliasing). The MFMA loop then does one
// ds_read_b128 per K-step instead of 8 scalar strided global loads per
// thread — removes ~6x VMEM insts/thread and the 4x redundant panel reads.
// Blocks 768..895: LDS-tiled 64x64 transposes of Wfc/Wproj -> bf16 [n][k].
// ---------------------------------------------------------------------------
#define BKP 264   // lbt row stride (k) in elements: 256 + 8 pad

__global__ __launch_bounds__(256)
void qkv_k(const float* __restrict__ x, const float* __restrict__ W,
           const float* __restrict__ bias,
           const float* __restrict__ Wfc, const float* __restrict__ Wproj,
           char* __restrict__ wsb)
{
    __shared__ float lt[64 * 65];
    __shared__ __align__(16) __bf16 lbt[16 * BKP];   // B^T panel, 8.25 KB
    const int bid = blockIdx.x, tid = threadIdx.x;

    if (bid >= 768) {
        const int tt = bid - 768;
        const float* src; __bf16* dst; int K, N, tile;
        if (tt < 64) { src = Wfc;   dst = (__bf16*)(wsb + B_WFCT); K = 256;  N = 1024; tile = tt; }
        else         { src = Wproj; dst = (__bf16*)(wsb + B_WPJT); K = 1024; N = 256;  tile = tt - 64; }
        const int nn = N >> 6;
        const int k0 = (tile / nn) * 64, n0 = (tile % nn) * 64;
        const int rr0 = tid >> 4, c4 = tid & 15;
        #pragma unroll
        for (int i = 0; i < 4; ++i) {
            const int rr = rr0 + i * 16;
            float4 v = *(const float4*)&src[(size_t)(k0 + rr) * N + n0 + c4 * 4];
            lt[rr * 65 + c4 * 4 + 0] = v.x; lt[rr * 65 + c4 * 4 + 1] = v.y;
            lt[rr * 65 + c4 * 4 + 2] = v.z; lt[rr * 65 + c4 * 4 + 3] = v.w;
        }
        __syncthreads();
        #pragma unroll
        for (int i = 0; i < 4; ++i) {
            const int rr = rr0 + i * 16;
            bf16x4 b;
            b.x = (__bf16)lt[(c4 * 4 + 0) * 65 + rr];
            b.y = (__bf16)lt[(c4 * 4 + 1) * 65 + rr];
            b.z = (__bf16)lt[(c4 * 4 + 2) * 65 + rr];
            b.w = (__bf16)lt[(c4 * 4 + 3) * 65 + rr];
            *(bf16x4*)&dst[(size_t)(n0 + rr) * K + k0 + c4 * 4] = b;
        }
        return;
    }

    const int lane = tid & 63, wv = tid >> 6;
    const int n0 = (bid >> 4) * 16;                   // shared by all 4 waves
    const int m0 = ((bid * 4 + wv) & 63) * 16;
    const int r = lane & 15, q = lane >> 4;

    // ---- cooperative stage: W[0:256][n0:n0+16] -> lbt[n][k] bf16 ----
    {
        const int kk = tid >> 2;            // 0..63
        const int c4 = (tid & 3) * 4;       // 0,4,8,12
        #pragma unroll
        for (int p = 0; p < 4; ++p) {
            const int k = p * 64 + kk;
            float4 w = *(const float4*)&W[(size_t)k * 768 + n0 + c4];
            lbt[(c4 + 0) * BKP + k] = (__bf16)w.x;
            lbt[(c4 + 1) * BKP + k] = (__bf16)w.y;
            lbt[(c4 + 2) * BKP + k] = (__bf16)w.z;
            lbt[(c4 + 3) * BKP + k] = (__bf16)w.w;
        }
    }
    __syncthreads();

    const float*  ap = x + (size_t)(m0 + r) * DM + q * 8;
    const __bf16* bl = &lbt[r * BKP + q * 8];

    f32x4 acc = {0.f, 0.f, 0.f, 0.f};
    #pragma unroll
    for (int kt = 0; kt < DM; kt += 32) {
        float4 a0 = *(const float4*)(ap + kt);
        float4 a1 = *(const float4*)(ap + kt + 4);
        bf16x8 af;
        af[0] = (__bf16)a0.x; af[1] = (__bf16)a0.y; af[2] = (__bf16)a0.z; af[3] = (__bf16)a0.w;
        af[4] = (__bf16)a1.x; af[5] = (__bf16)a1.y; af[6] = (__bf16)a1.z; af[7] = (__bf16)a1.w;
        bf16x8 bf = *(const bf16x8*)(bl + kt);
        acc = __builtin_amdgcn_mfma_f32_16x16x32_bf16(af, bf, acc, 0, 0, 0);
    }

    __half*  qh  = (__half*)(wsb + B_QH);
    __half*  kh  = (__half*)(wsb + B_KH);
    __bf16*  vtb = (__bf16*)(wsb + B_VT);
    const int n = n0 + r;                 // C col = lane&15
    const float bn = bias[n];
    const int h = n / 96, jj = n % 96;
    #pragma unroll
    for (int i = 0; i < 4; ++i) {
        const int m = m0 + q * 4 + i;     // C row = q*4 + i
        const float v = acc[i] + bn;
        const int b = m >> 9, t = m & 511;
        const int bh = b * NH + h;
        if (jj < 32)      qh[((size_t)(bh * SEQ + t)) * HC + jj]        = (__half)v;
        else if (jj < 64) kh[((size_t)(bh * SEQ + t)) * HC + (jj - 32)] = (__half)v;
        else              vtb[((size_t)(bh * HC + (jj - 64))) * SEQ + t] = (__bf16)v;
    }
}

// ---------------------------------------------------------------------------
// K2: L1-distance attention + residual, fp16-packed distance (unchanged —
// kept byte-identical this round for clean attribution).
// ---------------------------------------------------------------------------
#define QT 16
#define PSTRIDE 514

__global__ __launch_bounds__(512, 4)
void attn_k(const char* __restrict__ wsb, const float* __restrict__ xin,
            float* __restrict__ x1, const float* __restrict__ bproj,
            float* __restrict__ out)
{
    __shared__ __half2 qtile[QT * 16];
    __shared__ __bf16  pmat[QT * PSTRIDE];
    __shared__ float   psum[QT * 8];
    __shared__ float   pinv[QT];

    const __half*  qhg = (const __half*)(wsb + B_QH);
    const __half*  khg = (const __half*)(wsb + B_KH);
    const __bf16*  vtb = (const __bf16*)(wsb + B_VT);

    const int tid  = threadIdx.x;
    const int lane = tid & 63;
    const int wv   = tid >> 6;
    const int sg   = tid;                       // s index
    const int bh   = blockIdx.x >> 5;
    const int qbase = (blockIdx.x & 31) * QT;
    const float scale = 0.17677669529663687f;   // 1/sqrt(32)

    const __half2* kp = (const __half2*)(khg + ((size_t)(bh * SEQ + sg)) * HC);
    __half2 kr[16];
    #pragma unroll
    for (int j = 0; j < 16; ++j) kr[j] = kp[j];

    if (tid < 256) {
        const int t = tid >> 4, j = tid & 15;
        qtile[t * 16 + j] =
            *(const __half2*)(qhg + ((size_t)(bh * SEQ + qbase + t)) * HC + j * 2);
    }
    __syncthreads();

    #pragma unroll 4
    for (int t = 0; t < QT; ++t) {
        __half2 acc2 = __floats2half2_rn(0.f, 0.f);
        #pragma unroll
        for (int j = 0; j < 16; ++j) {
            __half2 dif = __hsub2(kr[j], qtile[t * 16 + j]);   // LDS broadcast
            unsigned u = (*(unsigned*)&dif) & 0x7FFF7FFFu;     // packed |.|
            acc2 = __hadd2(acc2, *(__half2*)&u);
        }
        const float d = __low2float(acc2) + __high2float(acc2);
        float w = 1.0f / (0.001f + d * scale);
        if (sg == qbase + t) w = 0.0f;          // diagonal
        float p = __expf(w);                    // w bounded: no max pass
        float se = p;
        #pragma unroll
        for (int off = 32; off >= 1; off >>= 1) se += __shfl_xor(se, off, 64);
        pmat[t * PSTRIDE + sg] = (__bf16)p;
        if (lane == 0) psum[t * 8 + wv] = se;
    }
    __syncthreads();

    if (tid < QT) {
        float s = 0.f;
        #pragma unroll
        for (int j = 0; j < 8; ++j) s += psum[tid * 8 + j];
        pinv[tid] = 1.0f / s;
    }
    __syncthreads();

    if (wv < 2) {
        const int r = lane & 15, q = lane >> 4;
        const __bf16* bp  = vtb + ((size_t)(bh * HC + wv * 16 + r)) * SEQ + q * 8;
        const __bf16* apm = &pmat[r * PSTRIDE + q * 8];
        f32x4 acc = {0.f, 0.f, 0.f, 0.f};
        #pragma unroll
        for (int kt = 0; kt < SEQ; kt += 32) {
            bf16x8 af = *(const bf16x8*)(apm + kt);
            bf16x8 bf = *(const bf16x8*)(bp + kt);
            acc = __builtin_amdgcn_mfma_f32_16x16x32_bf16(af, bf, acc, 0, 0, 0);
        }
        const int b = bh >> 3, hh = bh & 7;
        const int c = wv * 16 + r;
        const int col = hh * HC + c;
        const float bpn = bproj[col];
        #pragma unroll
        for (int i = 0; i < 4; ++i) {
            const int tl = q * 4 + i;
            const int t  = qbase + tl;
            const float v = acc[i] * pinv[tl];
            const int idx = ((b * SEQ + t) * DM) + col;
            const float res = xin[idx] + v;
            x1[idx]  = res;
            out[idx] = res + bpn;      // base: x1 + bproj; K3 atomically adds h@Wproj
        }
    }
}

// ---------------------------------------------------------------------------
// K3: fused MLP, split-K. NEW (this round): 8 k-slabs of 128 (was 4 of 256)
// -> 512 blocks = 2 blocks/CU = 2 waves/SIMD (was 1/SIMD, zero latency
// hiding). FC computes h[16][ns*128..+128) -> LDS bf16 [16][136]; PROJ
// computes the 128-wide k-slice partial and atomicAdds into out.
// ---------------------------------------------------------------------------
#define HSTR 136

__global__ __launch_bounds__(256)
void mlp_k(const float* __restrict__ X1, const char* __restrict__ wsb,
           const float* __restrict__ bfc, float* __restrict__ out)
{
    __shared__ __align__(16) __bf16 hs[16 * HSTR];   // 4.25 KB
    const __bf16* Wf = (const __bf16*)(wsb + B_WFCT);
    const __bf16* Wp = (const __bf16*)(wsb + B_WPJT);

    const int tid  = threadIdx.x;
    const int lane = tid & 63;
    const int wv   = tid >> 6;
    const int mt   = blockIdx.x & 63;
    const int ns   = blockIdx.x >> 6;            // k/n slab 0..7
    const int m0   = mt * 16;
    const int r    = lane & 15, q = lane >> 4;

    // ---- FC phase: h[16][ns*128 .. +128) ----
    {
        const float* ap = X1 + (size_t)(m0 + r) * DM + q * 8;
        f32x4 acc[2] = {};
        #pragma unroll
        for (int kt = 0; kt < DM; kt += 32) {
            float4 a0 = *(const float4*)(ap + kt);
            float4 a1 = *(const float4*)(ap + kt + 4);
            bf16x8 af;
            af[0] = (__bf16)a0.x; af[1] = (__bf16)a0.y; af[2] = (__bf16)a0.z; af[3] = (__bf16)a0.w;
            af[4] = (__bf16)a1.x; af[5] = (__bf16)a1.y; af[6] = (__bf16)a1.z; af[7] = (__bf16)a1.w;
            #pragma unroll
            for (int nt = 0; nt < 2; ++nt) {
                const int n0 = ns * 128 + (wv * 2 + nt) * 16;       // global h col
                bf16x8 bf = *(const bf16x8*)(Wf + (size_t)(n0 + r) * DM + q * 8 + kt);
                acc[nt] = __builtin_amdgcn_mfma_f32_16x16x32_bf16(af, bf, acc[nt], 0, 0, 0);
            }
        }
        #pragma unroll
        for (int nt = 0; nt < 2; ++nt) {
            const int nl = (wv * 2 + nt) * 16 + r;                  // local 0..127
            const float bn = bfc[ns * 128 + nl];
            #pragma unroll
            for (int i = 0; i < 4; ++i)
                hs[(q * 4 + i) * HSTR + nl] = (__bf16)qgelu(acc[nt][i] + bn);
        }
    }
    __syncthreads();

    // ---- PROJ phase: out[m0..+16][wv*64..+64) += h_slab @ Wp k-slice ----
    {
        f32x4 acc[4] = {};
        const __bf16* al = &hs[r * HSTR + q * 8];                   // A row = m
        #pragma unroll
        for (int kt = 0; kt < 128; kt += 32) {
            bf16x8 af = *(const bf16x8*)(al + kt);
            #pragma unroll
            for (int nt = 0; nt < 4; ++nt) {
                const int n0 = wv * 64 + nt * 16;
                bf16x8 bf = *(const bf16x8*)(Wp + (size_t)(n0 + r) * 1024 +
                                             ns * 128 + q * 8 + kt);
                acc[nt] = __builtin_amdgcn_mfma_f32_16x16x32_bf16(af, bf, acc[nt], 0, 0, 0);
            }
        }
        #pragma unroll
        for (int nt = 0; nt < 4; ++nt) {
            const int n = wv * 64 + nt * 16 + r;
            #pragma unroll
            for (int i = 0; i < 4; ++i) {
                const int m = m0 + q * 4 + i;
                atomicAdd(&out[(size_t)m * DM + n], acc[nt][i]);
            }
        }
    }
}

// ---------------------------------------------------------------------------
extern "C" void kernel_launch(void* const* d_in, const int* in_sizes, int n_in,
                              void* d_out, int out_size, void* d_ws, size_t ws_size,
                              hipStream_t stream)
{
    (void)in_sizes; (void)n_in; (void)out_size; (void)ws_size;
    const float* x     = (const float*)d_in[0];
    const float* Wqkv  = (const float*)d_in[1];
    const float* bqkv  = (const float*)d_in[2];
    const float* Wfc   = (const float*)d_in[3];
    const float* bfc   = (const float*)d_in[4];
    const float* Wproj = (const float*)d_in[5];
    const float* bproj = (const float*)d_in[6];
    float* out = (float*)d_out;
    char*  wsb = (char*)d_ws;
    float* x1  = (float*)(wsb + B_X1);

    // K1: QKV GEMM (LDS-staged B panel) + side-car Wfc/Wproj transposes
    qkv_k<<<896, 256, 0, stream>>>(x, Wqkv, bqkv, Wfc, Wproj, wsb);

    // K2: attention + residual -> x1; pre-init out = x1 + bproj
    attn_k<<<512, 512, 0, stream>>>(wsb, x, x1, bproj, out);

    // K3: out += qgelu(x1@Wfc+b) @ Wproj   (split-K x8, atomic accumulate)
    mlp_k<<<512, 256, 0, stream>>>(x1, wsb, bfc, out);
}

// Round 2
// 106.770 us; speedup vs baseline: 1.0232x; 1.0232x over previous
//
#include <hip/hip_runtime.h>
#include <hip/hip_bf16.h>
#include <hip/hip_fp16.h>

// Problem constants
#define DM   256
#define NH   8
#define HC   32
#define SEQ  512
#define MTOT 1024

// ---------- workspace layout (byte offsets) ----------
#define B_X1   0            // fp32 x1 [1024][256]      1 MB
#define B_QH   (1u<<20)     // fp16 q  [16][512][32]    512 KB
#define B_KH   0x180000u    // fp16 k  [16][512][32]    512 KB
#define B_VT   0x200000u    // bf16 vT [16][32][512]    512 KB
#define B_WFCT 0x280000u    // bf16 WfcT  [1024][256]   512 KB
#define B_WPJT 0x300000u    // bf16 WprojT [256][1024]  512 KB

typedef __attribute__((ext_vector_type(8))) __bf16 bf16x8;
typedef __attribute__((ext_vector_type(4))) __bf16 bf16x4;
typedef __attribute__((ext_vector_type(4))) float  f32x4;

__device__ __forceinline__ float qgelu(float x) {
    return x / (1.0f + __expf(-1.702f * x));
}

// ---------------------------------------------------------------------------
// K1: QKV GEMM (1024x768, K=256) + side-car weight transposes.
// B-panel W[0:256][n0:n0+16] staged ONCE through LDS (coalesced float4
// global reads, bf16 [n][k] transposed, stride 264). MFMA loop reads one
// ds_read_b128 per K-step instead of 8 scalar strided global loads.
// Blocks 768..895: LDS-tiled 64x64 transposes of Wfc/Wproj -> bf16 [n][k].
// ---------------------------------------------------------------------------
#define BKP 264   // lbt row stride (k) in elements: 256 + 8 pad

__global__ __launch_bounds__(256)
void qkv_k(const float* __restrict__ x, const float* __restrict__ W,
           const float* __restrict__ bias,
           const float* __restrict__ Wfc, const float* __restrict__ Wproj,
           char* __restrict__ wsb)
{
    __shared__ float lt[64 * 65];
    __shared__ __align__(16) __bf16 lbt[16 * BKP];   // B^T panel, 8.25 KB
    const int bid = blockIdx.x, tid = threadIdx.x;

    if (bid >= 768) {
        const int tt = bid - 768;
        const float* src; __bf16* dst; int K, N, tile;
        if (tt < 64) { src = Wfc;   dst = (__bf16*)(wsb + B_WFCT); K = 256;  N = 1024; tile = tt; }
        else         { src = Wproj; dst = (__bf16*)(wsb + B_WPJT); K = 1024; N = 256;  tile = tt - 64; }
        const int nn = N >> 6;
        const int k0 = (tile / nn) * 64, n0 = (tile % nn) * 64;
        const int rr0 = tid >> 4, c4 = tid & 15;
        #pragma unroll
        for (int i = 0; i < 4; ++i) {
            const int rr = rr0 + i * 16;
            float4 v = *(const float4*)&src[(size_t)(k0 + rr) * N + n0 + c4 * 4];
            lt[rr * 65 + c4 * 4 + 0] = v.x; lt[rr * 65 + c4 * 4 + 1] = v.y;
            lt[rr * 65 + c4 * 4 + 2] = v.z; lt[rr * 65 + c4 * 4 + 3] = v.w;
        }
        __syncthreads();
        #pragma unroll
        for (int i = 0; i < 4; ++i) {
            const int rr = rr0 + i * 16;
            bf16x4 b;
            b.x = (__bf16)lt[(c4 * 4 + 0) * 65 + rr];
            b.y = (__bf16)lt[(c4 * 4 + 1) * 65 + rr];
            b.z = (__bf16)lt[(c4 * 4 + 2) * 65 + rr];
            b.w = (__bf16)lt[(c4 * 4 + 3) * 65 + rr];
            *(bf16x4*)&dst[(size_t)(n0 + rr) * K + k0 + c4 * 4] = b;
        }
        return;
    }

    const int lane = tid & 63, wv = tid >> 6;
    const int n0 = (bid >> 4) * 16;                   // shared by all 4 waves
    const int m0 = ((bid * 4 + wv) & 63) * 16;
    const int r = lane & 15, q = lane >> 4;

    // ---- cooperative stage: W[0:256][n0:n0+16] -> lbt[n][k] bf16 ----
    {
        const int kk = tid >> 2;            // 0..63
        const int c4 = (tid & 3) * 4;       // 0,4,8,12
        #pragma unroll
        for (int p = 0; p < 4; ++p) {
            const int k = p * 64 + kk;
            float4 w = *(const float4*)&W[(size_t)k * 768 + n0 + c4];
            lbt[(c4 + 0) * BKP + k] = (__bf16)w.x;
            lbt[(c4 + 1) * BKP + k] = (__bf16)w.y;
            lbt[(c4 + 2) * BKP + k] = (__bf16)w.z;
            lbt[(c4 + 3) * BKP + k] = (__bf16)w.w;
        }
    }
    __syncthreads();

    const float*  ap = x + (size_t)(m0 + r) * DM + q * 8;
    const __bf16* bl = &lbt[r * BKP + q * 8];

    f32x4 acc = {0.f, 0.f, 0.f, 0.f};
    #pragma unroll
    for (int kt = 0; kt < DM; kt += 32) {
        float4 a0 = *(const float4*)(ap + kt);
        float4 a1 = *(const float4*)(ap + kt + 4);
        bf16x8 af;
        af[0] = (__bf16)a0.x; af[1] = (__bf16)a0.y; af[2] = (__bf16)a0.z; af[3] = (__bf16)a0.w;
        af[4] = (__bf16)a1.x; af[5] = (__bf16)a1.y; af[6] = (__bf16)a1.z; af[7] = (__bf16)a1.w;
        bf16x8 bf = *(const bf16x8*)(bl + kt);
        acc = __builtin_amdgcn_mfma_f32_16x16x32_bf16(af, bf, acc, 0, 0, 0);
    }

    __half*  qh  = (__half*)(wsb + B_QH);
    __half*  kh  = (__half*)(wsb + B_KH);
    __bf16*  vtb = (__bf16*)(wsb + B_VT);
    const int n = n0 + r;                 // C col = lane&15
    const float bn = bias[n];
    const int h = n / 96, jj = n % 96;
    #pragma unroll
    for (int i = 0; i < 4; ++i) {
        const int m = m0 + q * 4 + i;     // C row = q*4 + i
        const float v = acc[i] + bn;
        const int b = m >> 9, t = m & 511;
        const int bh = b * NH + h;
        if (jj < 32)      qh[((size_t)(bh * SEQ + t)) * HC + jj]        = (__half)v;
        else if (jj < 64) kh[((size_t)(bh * SEQ + t)) * HC + (jj - 32)] = (__half)v;
        else              vtb[((size_t)(bh * HC + (jj - 64))) * SEQ + t] = (__bf16)v;
    }
}

// ---------------------------------------------------------------------------
// K2: L1-distance attention + residual, fp16-packed distance (unchanged).
// ---------------------------------------------------------------------------
#define QT 16
#define PSTRIDE 514

__global__ __launch_bounds__(512, 4)
void attn_k(const char* __restrict__ wsb, const float* __restrict__ xin,
            float* __restrict__ x1, const float* __restrict__ bproj,
            float* __restrict__ out)
{
    __shared__ __half2 qtile[QT * 16];
    __shared__ __bf16  pmat[QT * PSTRIDE];
    __shared__ float   psum[QT * 8];
    __shared__ float   pinv[QT];

    const __half*  qhg = (const __half*)(wsb + B_QH);
    const __half*  khg = (const __half*)(wsb + B_KH);
    const __bf16*  vtb = (const __bf16*)(wsb + B_VT);

    const int tid  = threadIdx.x;
    const int lane = tid & 63;
    const int wv   = tid >> 6;
    const int sg   = tid;                       // s index
    const int bh   = blockIdx.x >> 5;
    const int qbase = (blockIdx.x & 31) * QT;
    const float scale = 0.17677669529663687f;   // 1/sqrt(32)

    const __half2* kp = (const __half2*)(khg + ((size_t)(bh * SEQ + sg)) * HC);
    __half2 kr[16];
    #pragma unroll
    for (int j = 0; j < 16; ++j) kr[j] = kp[j];

    if (tid < 256) {
        const int t = tid >> 4, j = tid & 15;
        qtile[t * 16 + j] =
            *(const __half2*)(qhg + ((size_t)(bh * SEQ + qbase + t)) * HC + j * 2);
    }
    __syncthreads();

    #pragma unroll 4
    for (int t = 0; t < QT; ++t) {
        __half2 acc2 = __floats2half2_rn(0.f, 0.f);
        #pragma unroll
        for (int j = 0; j < 16; ++j) {
            __half2 dif = __hsub2(kr[j], qtile[t * 16 + j]);   // LDS broadcast
            unsigned u = (*(unsigned*)&dif) & 0x7FFF7FFFu;     // packed |.|
            acc2 = __hadd2(acc2, *(__half2*)&u);
        }
        const float d = __low2float(acc2) + __high2float(acc2);
        float w = 1.0f / (0.001f + d * scale);
        if (sg == qbase + t) w = 0.0f;          // diagonal
        float p = __expf(w);                    // w bounded: no max pass
        float se = p;
        #pragma unroll
        for (int off = 32; off >= 1; off >>= 1) se += __shfl_xor(se, off, 64);
        pmat[t * PSTRIDE + sg] = (__bf16)p;
        if (lane == 0) psum[t * 8 + wv] = se;
    }
    __syncthreads();

    if (tid < QT) {
        float s = 0.f;
        #pragma unroll
        for (int j = 0; j < 8; ++j) s += psum[tid * 8 + j];
        pinv[tid] = 1.0f / s;
    }
    __syncthreads();

    if (wv < 2) {
        const int r = lane & 15, q = lane >> 4;
        const __bf16* bp  = vtb + ((size_t)(bh * HC + wv * 16 + r)) * SEQ + q * 8;
        const __bf16* apm = &pmat[r * PSTRIDE + q * 8];
        f32x4 acc = {0.f, 0.f, 0.f, 0.f};
        #pragma unroll
        for (int kt = 0; kt < SEQ; kt += 32) {
            bf16x8 af = *(const bf16x8*)(apm + kt);
            bf16x8 bf = *(const bf16x8*)(bp + kt);
            acc = __builtin_amdgcn_mfma_f32_16x16x32_bf16(af, bf, acc, 0, 0, 0);
        }
        const int b = bh >> 3, hh = bh & 7;
        const int c = wv * 16 + r;
        const int col = hh * HC + c;
        const float bpn = bproj[col];
        #pragma unroll
        for (int i = 0; i < 4; ++i) {
            const int tl = q * 4 + i;
            const int t  = qbase + tl;
            const float v = acc[i] * pinv[tl];
            const int idx = ((b * SEQ + t) * DM) + col;
            const float res = xin[idx] + v;
            x1[idx]  = res;
            out[idx] = res + bpn;      // base: x1 + bproj; K3 atomically adds h@Wproj
        }
    }
}

// ---------------------------------------------------------------------------
// K3: fused MLP, split-K x4 (round-0 atomic count: 1M), but 512-thread
// blocks (8 waves) -> 2 waves/SIMD instead of 1, at IDENTICAL atomic
// traffic and identical total MFMA work. FC: each of 8 waves computes 2
// n-tiles of the 256-wide h-slab -> LDS bf16 [16][264]. PROJ: each wave
// covers 32 out-cols over the full 256-deep k-slice, atomicAdds into out.
// ---------------------------------------------------------------------------
#define HSTR 264

__global__ __launch_bounds__(512)
void mlp_k(const float* __restrict__ X1, const char* __restrict__ wsb,
           const float* __restrict__ bfc, float* __restrict__ out)
{
    __shared__ __align__(16) __bf16 hs[16 * HSTR];   // 8.25 KB
    const __bf16* Wf = (const __bf16*)(wsb + B_WFCT);
    const __bf16* Wp = (const __bf16*)(wsb + B_WPJT);

    const int tid  = threadIdx.x;
    const int lane = tid & 63;
    const int wv   = tid >> 6;                   // 0..7
    const int mt   = blockIdx.x & 63;
    const int ns   = blockIdx.x >> 6;            // k/n slab 0..3
    const int m0   = mt * 16;
    const int r    = lane & 15, q = lane >> 4;

    // ---- FC phase: h[16][ns*256 .. +256) ----
    {
        const float* ap = X1 + (size_t)(m0 + r) * DM + q * 8;
        f32x4 acc[2] = {};
        #pragma unroll
        for (int kt = 0; kt < DM; kt += 32) {
            float4 a0 = *(const float4*)(ap + kt);
            float4 a1 = *(const float4*)(ap + kt + 4);
            bf16x8 af;
            af[0] = (__bf16)a0.x; af[1] = (__bf16)a0.y; af[2] = (__bf16)a0.z; af[3] = (__bf16)a0.w;
            af[4] = (__bf16)a1.x; af[5] = (__bf16)a1.y; af[6] = (__bf16)a1.z; af[7] = (__bf16)a1.w;
            #pragma unroll
            for (int nt = 0; nt < 2; ++nt) {
                const int n0 = ns * 256 + (wv * 2 + nt) * 16;       // global h col
                bf16x8 bf = *(const bf16x8*)(Wf + (size_t)(n0 + r) * DM + q * 8 + kt);
                acc[nt] = __builtin_amdgcn_mfma_f32_16x16x32_bf16(af, bf, acc[nt], 0, 0, 0);
            }
        }
        #pragma unroll
        for (int nt = 0; nt < 2; ++nt) {
            const int nl = (wv * 2 + nt) * 16 + r;                  // local 0..255
            const float bn = bfc[ns * 256 + nl];
            #pragma unroll
            for (int i = 0; i < 4; ++i)
                hs[(q * 4 + i) * HSTR + nl] = (__bf16)qgelu(acc[nt][i] + bn);
        }
    }
    __syncthreads();

    // ---- PROJ phase: out[m0..+16][wv*32..+32) += h_slab @ Wp k-slice ----
    {
        f32x4 acc[2] = {};
        const __bf16* al = &hs[r * HSTR + q * 8];                   // A row = m
        #pragma unroll
        for (int kt = 0; kt < 256; kt += 32) {
            bf16x8 af = *(const bf16x8*)(al + kt);
            #pragma unroll
            for (int nt = 0; nt < 2; ++nt) {
                const int n0 = wv * 32 + nt * 16;
                bf16x8 bf = *(const bf16x8*)(Wp + (size_t)(n0 + r) * 1024 +
                                             ns * 256 + q * 8 + kt);
                acc[nt] = __builtin_amdgcn_mfma_f32_16x16x32_bf16(af, bf, acc[nt], 0, 0, 0);
            }
        }
        #pragma unroll
        for (int nt = 0; nt < 2; ++nt) {
            const int n = wv * 32 + nt * 16 + r;
            #pragma unroll
            for (int i = 0; i < 4; ++i) {
                const int m = m0 + q * 4 + i;
                atomicAdd(&out[(size_t)m * DM + n], acc[nt][i]);
            }
        }
    }
}

// ---------------------------------------------------------------------------
extern "C" void kernel_launch(void* const* d_in, const int* in_sizes, int n_in,
                              void* d_out, int out_size, void* d_ws, size_t ws_size,
                              hipStream_t stream)
{
    (void)in_sizes; (void)n_in; (void)out_size; (void)ws_size;
    const float* x     = (const float*)d_in[0];
    const float* Wqkv  = (const float*)d_in[1];
    const float* bqkv  = (const float*)d_in[2];
    const float* Wfc   = (const float*)d_in[3];
    const float* bfc   = (const float*)d_in[4];
    const float* Wproj = (const float*)d_in[5];
    const float* bproj = (const float*)d_in[6];
    float* out = (float*)d_out;
    char*  wsb = (char*)d_ws;
    float* x1  = (float*)(wsb + B_X1);

    // K1: QKV GEMM (LDS-staged B panel) + side-car Wfc/Wproj transposes
    qkv_k<<<896, 256, 0, stream>>>(x, Wqkv, bqkv, Wfc, Wproj, wsb);

    // K2: attention + residual -> x1; pre-init out = x1 + bproj
    attn_k<<<512, 512, 0, stream>>>(wsb, x, x1, bproj, out);

    // K3: out += qgelu(x1@Wfc+b) @ Wproj  (split-K x4, 512-thr blocks)
    mlp_k<<<256, 512, 0, stream>>>(x1, wsb, bfc, out);
}